// Round 1
// baseline (1231.706 us; speedup 1.0000x reference)
//
#include <hip/hip_runtime.h>

// N=50000, E=600000, D=128, R=500 — all fp32 (+int32 indices).
// out = relu( (scatter_sum(h[src]+emb[etype], dst) * norm) @ Wn
//             + h @ (deg>0 ? Wl : We) )
// Linearity: GEMM moved from edge side (E rows) to node side (N rows).

#define DIM 128
#define DIM4 32   // DIM/4

__device__ inline void fma4(float4& acc, float s, const float4& w) {
    acc.x = fmaf(s, w.x, acc.x);
    acc.y = fmaf(s, w.y, acc.y);
    acc.z = fmaf(s, w.z, acc.z);
    acc.w = fmaf(s, w.w, acc.w);
}

// ---------------- scatter: acc[dst] += h[src] + emb[etype]; deg[dst]++ -----
// 32 lanes per edge, float4 per lane. 8 edges per 256-thread block.
__global__ __launch_bounds__(256) void scatter_kernel(
    const float4* __restrict__ h4,     // [N][32]
    const float4* __restrict__ emb4,   // [R][32]
    const int* __restrict__ src,
    const int* __restrict__ dst,
    const int* __restrict__ etype,
    float* __restrict__ acc,           // [N][128]
    int* __restrict__ deg,             // [N]
    int E)
{
    int e = blockIdx.x * 8 + (threadIdx.x >> 5);
    if (e >= E) return;
    int lane = threadIdx.x & 31;
    int s = src[e];
    int d = dst[e];
    int t = etype[e];
    float4 hv = h4[(size_t)s * DIM4 + lane];
    float4 rv = emb4[(size_t)t * DIM4 + lane];
    float* base = acc + (size_t)d * DIM + lane * 4;
    unsafeAtomicAdd(base + 0, hv.x + rv.x);
    unsafeAtomicAdd(base + 1, hv.y + rv.y);
    unsafeAtomicAdd(base + 2, hv.z + rv.z);
    unsafeAtomicAdd(base + 3, hv.w + rv.w);
    if (lane == 0) atomicAdd(deg + d, 1);
}

// ---------------- fused finalize GEMM --------------------------------------
// Per 64-node tile: As[n][0:128] = acc[n]*norm[n], As[n][128:256] = h[n].
// out[n] = relu( As[n][0:128] @ Wn  +  As[n][128:256] @ (deg[n]>0 ? Wl : We) )
// Thread layout: cg = t&31 -> 4 output cols (cg*4..+3); ng = t>>5 -> 8 nodes.

__device__ inline void accum_uniform(const float4* __restrict__ W4,
                                     const float (*As)[256],
                                     int n0, int koff, int cg, float4* accv)
{
    for (int k = 0; k < DIM; k += 4) {
        float4 w0 = W4[(k + 0) * DIM4 + cg];
        float4 w1 = W4[(k + 1) * DIM4 + cg];
        float4 w2 = W4[(k + 2) * DIM4 + cg];
        float4 w3 = W4[(k + 3) * DIM4 + cg];
        #pragma unroll
        for (int i = 0; i < 8; ++i) {
            float4 a = *((const float4*)&As[n0 + i][koff + k]);
            fma4(accv[i], a.x, w0);
            fma4(accv[i], a.y, w1);
            fma4(accv[i], a.z, w2);
            fma4(accv[i], a.w, w3);
        }
    }
}

__global__ __launch_bounds__(256) void finalize_kernel(
    const float4* __restrict__ acc4,   // [N][32] (scatter result)
    const float4* __restrict__ h4,     // [N][32]
    const float* __restrict__ norm,    // [N]
    const int* __restrict__ deg,       // [N]
    const float4* __restrict__ Wn4,    // [128][32]
    const float4* __restrict__ Wl4,
    const float4* __restrict__ We4,
    float4* __restrict__ out4,         // [N][32]
    int N)
{
    __shared__ float As[64][256];      // 64 KB
    int t = threadIdx.x;
    int nbase = blockIdx.x * 64;

    // ---- load phase: 4096 float4 slots, 16 per thread ----
    #pragma unroll
    for (int i = 0; i < 16; ++i) {
        int linear = t + i * 256;        // 0..4095
        int node = linear >> 6;          // 0..63
        int q = linear & 63;             // 0..63 (quad within stacked row)
        int gn = nbase + node;
        float4 v = make_float4(0.f, 0.f, 0.f, 0.f);
        if (gn < N) {
            if (q < DIM4) {
                float nm = norm[gn];
                float4 a = acc4[(size_t)gn * DIM4 + q];
                v = make_float4(a.x * nm, a.y * nm, a.z * nm, a.w * nm);
            } else {
                v = h4[(size_t)gn * DIM4 + (q - DIM4)];
            }
        }
        *((float4*)&As[node][q * 4]) = v;
    }
    __syncthreads();

    int cg = t & 31;        // col group -> cols cg*4..cg*4+3
    int ng = t >> 5;        // node group
    int n0 = ng * 8;        // 8 nodes per thread

    float4 accv[8];
    #pragma unroll
    for (int i = 0; i < 8; ++i) accv[i] = make_float4(0.f, 0.f, 0.f, 0.f);

    // phase 1: neighbor part (As cols 0..127) @ Wn
    accum_uniform(Wn4, As, n0, 0, cg, accv);

    // phase 2: self-loop part (As cols 128..255) @ (deg>0 ? Wl : We)
    bool m[8];
    bool all1 = true, all0 = true;
    #pragma unroll
    for (int i = 0; i < 8; ++i) {
        int gn = nbase + n0 + i;
        bool mi = (gn < N) ? (deg[gn] > 0) : true;
        m[i] = mi;
        all1 &= mi;
        all0 &= !mi;
    }
    if (all1) {
        accum_uniform(Wl4, As, n0, DIM, cg, accv);
    } else if (all0) {
        accum_uniform(We4, As, n0, DIM, cg, accv);
    } else {
        // rare mixed tile: load both, per-node select
        for (int k = 0; k < DIM; k += 4) {
            float4 l0 = Wl4[(k + 0) * DIM4 + cg];
            float4 l1 = Wl4[(k + 1) * DIM4 + cg];
            float4 l2 = Wl4[(k + 2) * DIM4 + cg];
            float4 l3 = Wl4[(k + 3) * DIM4 + cg];
            float4 e0 = We4[(k + 0) * DIM4 + cg];
            float4 e1 = We4[(k + 1) * DIM4 + cg];
            float4 e2 = We4[(k + 2) * DIM4 + cg];
            float4 e3 = We4[(k + 3) * DIM4 + cg];
            #pragma unroll
            for (int i = 0; i < 8; ++i) {
                float4 a = *((const float4*)&As[n0 + i][DIM + k]);
                float4 w0 = m[i] ? l0 : e0;
                float4 w1 = m[i] ? l1 : e1;
                float4 w2 = m[i] ? l2 : e2;
                float4 w3 = m[i] ? l3 : e3;
                fma4(accv[i], a.x, w0);
                fma4(accv[i], a.y, w1);
                fma4(accv[i], a.z, w2);
                fma4(accv[i], a.w, w3);
            }
        }
    }

    // epilogue: relu + store
    #pragma unroll
    for (int i = 0; i < 8; ++i) {
        int gn = nbase + n0 + i;
        if (gn < N) {
            float4 r = accv[i];
            r.x = fmaxf(r.x, 0.f);
            r.y = fmaxf(r.y, 0.f);
            r.z = fmaxf(r.z, 0.f);
            r.w = fmaxf(r.w, 0.f);
            out4[(size_t)gn * DIM4 + cg] = r;
        }
    }
}

extern "C" void kernel_launch(void* const* d_in, const int* in_sizes, int n_in,
                              void* d_out, int out_size, void* d_ws, size_t ws_size,
                              hipStream_t stream)
{
    const float* h    = (const float*)d_in[0];
    const float* norm = (const float*)d_in[1];
    const float* emb  = (const float*)d_in[2];
    const float* Wn   = (const float*)d_in[3];
    const float* Wl   = (const float*)d_in[4];
    const float* We   = (const float*)d_in[5];
    const int* src    = (const int*)d_in[6];
    const int* dst    = (const int*)d_in[7];
    const int* etype  = (const int*)d_in[8];

    const int N = in_sizes[1];   // norm has N elements
    const int E = in_sizes[6];

    float* acc = (float*)d_ws;                                   // N*128 fp32
    int*   deg = (int*)((char*)d_ws + (size_t)N * DIM * sizeof(float));

    // zero acc + deg (ws is re-poisoned to 0xAA before every timed launch)
    hipMemsetAsync(d_ws, 0, (size_t)N * DIM * sizeof(float) + (size_t)N * sizeof(int),
                   stream);

    scatter_kernel<<<dim3((E + 7) / 8), dim3(256), 0, stream>>>(
        (const float4*)h, (const float4*)emb, src, dst, etype, acc, deg, E);

    finalize_kernel<<<dim3((N + 63) / 64), dim3(256), 0, stream>>>(
        (const float4*)acc, (const float4*)h, norm, deg,
        (const float4*)Wn, (const float4*)Wl, (const float4*)We,
        (float4*)d_out, N);
}

// Round 2
// 418.253 us; speedup vs baseline: 2.9449x; 2.9449x over previous
//
#include <hip/hip_runtime.h>

// N=50000, E=600000, D=128, R=500 — all fp32 (+int32 indices).
// out = relu( (gather_sum(h[src]+emb[etype] over in-edges) * norm) @ Wn
//             + h @ (deg>0 ? Wl : We) )
// R2: atomic scatter (76.8M fp atomics, 1030us) replaced by on-the-fly edge
// bucketing (CSR-ish) + gather-side reduction fused into the finalize GEMM.

#define DIM 128
#define DIM4 32   // DIM/4

__device__ inline void fma4(float4& acc, float s, const float4& w) {
    acc.x = fmaf(s, w.x, acc.x);
    acc.y = fmaf(s, w.y, acc.y);
    acc.z = fmaf(s, w.z, acc.z);
    acc.w = fmaf(s, w.w, acc.w);
}

// ---------- k1: in-degree histogram ---------------------------------------
__global__ __launch_bounds__(256) void deg_kernel(
    const int* __restrict__ dst, int* __restrict__ deg, int E)
{
    int e = blockIdx.x * 256 + threadIdx.x;
    if (e < E) atomicAdd(deg + dst[e], 1);
}

// ---------- k2: offset allocation (wave scan + 1 atomic per wave) ---------
// cursor[n] = start offset of node n's bucket. Order across waves arbitrary.
__global__ __launch_bounds__(256) void alloc_kernel(
    const int* __restrict__ deg, int* __restrict__ counter,
    int* __restrict__ cursor, int N)
{
    int n = blockIdx.x * 256 + threadIdx.x;
    int lane = threadIdx.x & 63;
    int x = (n < N) ? deg[n] : 0;
    // inclusive wave scan
    int incl = x;
    #pragma unroll
    for (int o = 1; o < 64; o <<= 1) {
        int v = __shfl_up(incl, o);
        if (lane >= o) incl += v;
    }
    int total = __shfl(incl, 63);
    int base = 0;
    if (lane == 0) base = atomicAdd(counter, total);
    base = __shfl(base, 0);
    if (n < N) cursor[n] = base + incl - x;   // exclusive start
}

// ---------- k3: bucket fill -----------------------------------------------
// After this, cursor[n] == start[n] + deg[n] (i.e. end). start = end - deg.
__global__ __launch_bounds__(256) void fill_kernel(
    const int* __restrict__ src, const int* __restrict__ dst,
    const int* __restrict__ etype, int* __restrict__ cursor,
    unsigned* __restrict__ buckets, int E)
{
    int e = blockIdx.x * 256 + threadIdx.x;
    if (e >= E) return;
    int d = dst[e];
    int p = atomicAdd(cursor + d, 1);
    buckets[p] = (unsigned)src[e] | ((unsigned)etype[e] << 17);
}

// ---------- k4: fused gather + finalize GEMM ------------------------------
// Per 64-node tile: As[n][0:128] = (sum over in-edges of h[src]+emb[et]) * norm
//                   As[n][128:256] = h[n]
// out[n] = relu( As[n][0:128] @ Wn + As[n][128:256] @ (deg[n]>0 ? Wl : We) )

__device__ inline void accum_uniform(const float4* __restrict__ W4,
                                     const float (*As)[256],
                                     int n0, int koff, int cg, float4* accv)
{
    for (int k = 0; k < DIM; k += 4) {
        float4 w0 = W4[(k + 0) * DIM4 + cg];
        float4 w1 = W4[(k + 1) * DIM4 + cg];
        float4 w2 = W4[(k + 2) * DIM4 + cg];
        float4 w3 = W4[(k + 3) * DIM4 + cg];
        #pragma unroll
        for (int i = 0; i < 8; ++i) {
            float4 a = *((const float4*)&As[n0 + i][koff + k]);
            fma4(accv[i], a.x, w0);
            fma4(accv[i], a.y, w1);
            fma4(accv[i], a.z, w2);
            fma4(accv[i], a.w, w3);
        }
    }
}

__global__ __launch_bounds__(256) void finalize_kernel(
    const float4* __restrict__ h4,     // [N][32]
    const float4* __restrict__ emb4,   // [R][32]
    const float* __restrict__ norm,    // [N]
    const int* __restrict__ deg,       // [N]
    const int* __restrict__ cursor,    // [N] (== end offset after k3)
    const unsigned* __restrict__ buckets, // [E] packed (src | etype<<17)
    const float4* __restrict__ Wn4,    // [128][32]
    const float4* __restrict__ Wl4,
    const float4* __restrict__ We4,
    float4* __restrict__ out4,         // [N][32]
    int N)
{
    __shared__ float As[64][256];      // 64 KB
    int t = threadIdx.x;
    int nbase = blockIdx.x * 64;

    // ---- self-loop half: As[node][128:256] = h[node] (coalesced) ----
    #pragma unroll
    for (int i = 0; i < 8; ++i) {
        int linear = t + i * 256;        // 0..2047
        int node = linear >> 5;          // 0..63
        int q = linear & 31;
        int gn = nbase + node;
        float4 v = (gn < N) ? h4[(size_t)gn * DIM4 + q]
                            : make_float4(0.f, 0.f, 0.f, 0.f);
        *((float4*)&As[node][DIM + q * 4]) = v;
    }

    // ---- neighbor half: gather-reduce over bucketed in-edges ----
    // 8 groups of 32 lanes; group g handles nodes g*8 .. g*8+7.
    {
        int g = t >> 5;
        int lane = t & 31;
        for (int i = 0; i < 8; ++i) {
            int node = g * 8 + i;
            int gn = nbase + node;
            float4 a = make_float4(0.f, 0.f, 0.f, 0.f);
            if (gn < N) {
                int end = cursor[gn];
                int d   = deg[gn];
                int e   = end - d;
                for (; e + 1 < end; e += 2) {
                    unsigned p0 = buckets[e];
                    unsigned p1 = buckets[e + 1];
                    int s0 = p0 & 0x1FFFF, t0 = p0 >> 17;
                    int s1 = p1 & 0x1FFFF, t1 = p1 >> 17;
                    float4 hv0 = h4[(size_t)s0 * DIM4 + lane];
                    float4 rv0 = emb4[(size_t)t0 * DIM4 + lane];
                    float4 hv1 = h4[(size_t)s1 * DIM4 + lane];
                    float4 rv1 = emb4[(size_t)t1 * DIM4 + lane];
                    a.x += (hv0.x + rv0.x) + (hv1.x + rv1.x);
                    a.y += (hv0.y + rv0.y) + (hv1.y + rv1.y);
                    a.z += (hv0.z + rv0.z) + (hv1.z + rv1.z);
                    a.w += (hv0.w + rv0.w) + (hv1.w + rv1.w);
                }
                if (e < end) {
                    unsigned p0 = buckets[e];
                    int s0 = p0 & 0x1FFFF, t0 = p0 >> 17;
                    float4 hv0 = h4[(size_t)s0 * DIM4 + lane];
                    float4 rv0 = emb4[(size_t)t0 * DIM4 + lane];
                    a.x += hv0.x + rv0.x;
                    a.y += hv0.y + rv0.y;
                    a.z += hv0.z + rv0.z;
                    a.w += hv0.w + rv0.w;
                }
                float nm = norm[gn];
                a.x *= nm; a.y *= nm; a.z *= nm; a.w *= nm;
            }
            *((float4*)&As[node][lane * 4]) = a;
        }
    }
    __syncthreads();

    // ---- GEMM phase ----
    int cg = t & 31;        // col group -> cols cg*4..cg*4+3
    int ng = t >> 5;        // node group
    int n0 = ng * 8;        // 8 nodes per thread

    float4 accv[8];
    #pragma unroll
    for (int i = 0; i < 8; ++i) accv[i] = make_float4(0.f, 0.f, 0.f, 0.f);

    // phase 1: neighbor part (As cols 0..127) @ Wn
    accum_uniform(Wn4, As, n0, 0, cg, accv);

    // phase 2: self-loop part (As cols 128..255) @ (deg>0 ? Wl : We)
    bool m[8];
    bool all1 = true, all0 = true;
    #pragma unroll
    for (int i = 0; i < 8; ++i) {
        int gn = nbase + n0 + i;
        bool mi = (gn < N) ? (deg[gn] > 0) : true;
        m[i] = mi;
        all1 &= mi;
        all0 &= !mi;
    }
    if (all1) {
        accum_uniform(Wl4, As, n0, DIM, cg, accv);
    } else if (all0) {
        accum_uniform(We4, As, n0, DIM, cg, accv);
    } else {
        // rare mixed tile: load both, per-node select
        for (int k = 0; k < DIM; k += 4) {
            float4 l0 = Wl4[(k + 0) * DIM4 + cg];
            float4 l1 = Wl4[(k + 1) * DIM4 + cg];
            float4 l2 = Wl4[(k + 2) * DIM4 + cg];
            float4 l3 = Wl4[(k + 3) * DIM4 + cg];
            float4 e0 = We4[(k + 0) * DIM4 + cg];
            float4 e1 = We4[(k + 1) * DIM4 + cg];
            float4 e2 = We4[(k + 2) * DIM4 + cg];
            float4 e3 = We4[(k + 3) * DIM4 + cg];
            #pragma unroll
            for (int i = 0; i < 8; ++i) {
                float4 a = *((const float4*)&As[n0 + i][DIM + k]);
                float4 w0 = m[i] ? l0 : e0;
                float4 w1 = m[i] ? l1 : e1;
                float4 w2 = m[i] ? l2 : e2;
                float4 w3 = m[i] ? l3 : e3;
                fma4(accv[i], a.x, w0);
                fma4(accv[i], a.y, w1);
                fma4(accv[i], a.z, w2);
                fma4(accv[i], a.w, w3);
            }
        }
    }

    // epilogue: relu + store
    #pragma unroll
    for (int i = 0; i < 8; ++i) {
        int gn = nbase + n0 + i;
        if (gn < N) {
            float4 r = accv[i];
            r.x = fmaxf(r.x, 0.f);
            r.y = fmaxf(r.y, 0.f);
            r.z = fmaxf(r.z, 0.f);
            r.w = fmaxf(r.w, 0.f);
            out4[(size_t)gn * DIM4 + cg] = r;
        }
    }
}

extern "C" void kernel_launch(void* const* d_in, const int* in_sizes, int n_in,
                              void* d_out, int out_size, void* d_ws, size_t ws_size,
                              hipStream_t stream)
{
    const float* h    = (const float*)d_in[0];
    const float* norm = (const float*)d_in[1];
    const float* emb  = (const float*)d_in[2];
    const float* Wn   = (const float*)d_in[3];
    const float* Wl   = (const float*)d_in[4];
    const float* We   = (const float*)d_in[5];
    const int* src    = (const int*)d_in[6];
    const int* dst    = (const int*)d_in[7];
    const int* etype  = (const int*)d_in[8];

    const int N = in_sizes[1];   // norm has N elements
    const int E = in_sizes[6];

    // ws layout: deg[N] | counter[1] | cursor[N] | buckets[E]
    int* deg        = (int*)d_ws;
    int* counter    = deg + N;
    int* cursor     = counter + 1;
    unsigned* buckets = (unsigned*)(cursor + N);

    // zero deg + counter only (~200 KB)
    hipMemsetAsync(d_ws, 0, (size_t)(N + 1) * sizeof(int), stream);

    deg_kernel<<<dim3((E + 255) / 256), dim3(256), 0, stream>>>(dst, deg, E);

    alloc_kernel<<<dim3((N + 255) / 256), dim3(256), 0, stream>>>(
        deg, counter, cursor, N);

    fill_kernel<<<dim3((E + 255) / 256), dim3(256), 0, stream>>>(
        src, dst, etype, cursor, buckets, E);

    finalize_kernel<<<dim3((N + 63) / 64), dim3(256), 0, stream>>>(
        (const float4*)h, (const float4*)emb, norm, deg, cursor, buckets,
        (const float4*)Wn, (const float4*)Wl, (const float4*)We,
        (float4*)d_out, N);
}

// Round 3
// 301.069 us; speedup vs baseline: 4.0911x; 1.3892x over previous
//
#include <hip/hip_runtime.h>

// N=50000, E=600000, D=128, R=500 — all fp32 (+int32 indices).
// out = relu( (gather_sum(h[src]+emb[etype] over in-edges) * norm) @ Wn
//             + h @ (deg>0 ? Wl : We) )
// R3: gather split out of the GEMM. Gather kernel = no LDS, low VGPR, 8 waves/
// SIMD, 4-edge unroll (8 gathers in flight / group) -> latency hidden by
// TLP+ILP. GEMM kernel = pure LDS-staged [64x256]@[256x128].

#define DIM 128
#define DIM4 32   // DIM/4

__device__ inline void fma4(float4& acc, float s, const float4& w) {
    acc.x = fmaf(s, w.x, acc.x);
    acc.y = fmaf(s, w.y, acc.y);
    acc.z = fmaf(s, w.z, acc.z);
    acc.w = fmaf(s, w.w, acc.w);
}
__device__ inline void add4(float4& a, const float4& u, const float4& v) {
    a.x += u.x + v.x; a.y += u.y + v.y; a.z += u.z + v.z; a.w += u.w + v.w;
}

// ---------- k1: in-degree histogram (int4-vectorized) ---------------------
__global__ __launch_bounds__(256) void deg_kernel(
    const int4* __restrict__ dst4, int* __restrict__ deg, int E4)
{
    int i = blockIdx.x * 256 + threadIdx.x;
    if (i < E4) {
        int4 d = dst4[i];
        atomicAdd(deg + d.x, 1);
        atomicAdd(deg + d.y, 1);
        atomicAdd(deg + d.z, 1);
        atomicAdd(deg + d.w, 1);
    }
}

// ---------- k2: offset allocation (wave scan + 1 atomic per wave) ---------
__global__ __launch_bounds__(256) void alloc_kernel(
    const int* __restrict__ deg, int* __restrict__ counter,
    int* __restrict__ cursor, int N)
{
    int n = blockIdx.x * 256 + threadIdx.x;
    int lane = threadIdx.x & 63;
    int x = (n < N) ? deg[n] : 0;
    int incl = x;
    #pragma unroll
    for (int o = 1; o < 64; o <<= 1) {
        int v = __shfl_up(incl, o);
        if (lane >= o) incl += v;
    }
    int total = __shfl(incl, 63);
    int base = 0;
    if (lane == 0) base = atomicAdd(counter, total);
    base = __shfl(base, 0);
    if (n < N) cursor[n] = base + incl - x;   // exclusive start
}

// ---------- k3: bucket fill -----------------------------------------------
// After this, cursor[n] == start[n] + deg[n] (end). start = end - deg.
__global__ __launch_bounds__(256) void fill_kernel(
    const int* __restrict__ src, const int* __restrict__ dst,
    const int* __restrict__ etype, int* __restrict__ cursor,
    unsigned* __restrict__ buckets, int E)
{
    int e = blockIdx.x * 256 + threadIdx.x;
    if (e >= E) return;
    int d = dst[e];
    int p = atomicAdd(cursor + d, 1);
    buckets[p] = (unsigned)src[e] | ((unsigned)etype[e] << 17);
}

// ---------- k4: gather-reduce ---------------------------------------------
// One 32-lane group per node; 4-edge unroll = 8 independent 512B gathers in
// flight. aggn[n] = (sum h[src]+emb[et]) * norm[n]. No LDS, low VGPR.
__global__ __launch_bounds__(256) void gather_kernel(
    const float4* __restrict__ h4,
    const float4* __restrict__ emb4,
    const float* __restrict__ norm,
    const int* __restrict__ deg,
    const int* __restrict__ cursor,
    const unsigned* __restrict__ buckets,
    float4* __restrict__ aggn4,        // [N][32]
    int N)
{
    int n = blockIdx.x * 8 + (threadIdx.x >> 5);
    if (n >= N) return;
    int lane = threadIdx.x & 31;
    int end = cursor[n];
    int d   = deg[n];
    int e   = end - d;

    float4 a = make_float4(0.f, 0.f, 0.f, 0.f);
    for (; e + 3 < end; e += 4) {
        unsigned p0 = buckets[e + 0];
        unsigned p1 = buckets[e + 1];
        unsigned p2 = buckets[e + 2];
        unsigned p3 = buckets[e + 3];
        float4 h0 = h4[(size_t)(p0 & 0x1FFFF) * DIM4 + lane];
        float4 r0 = emb4[(size_t)(p0 >> 17) * DIM4 + lane];
        float4 h1 = h4[(size_t)(p1 & 0x1FFFF) * DIM4 + lane];
        float4 r1 = emb4[(size_t)(p1 >> 17) * DIM4 + lane];
        float4 h2 = h4[(size_t)(p2 & 0x1FFFF) * DIM4 + lane];
        float4 r2 = emb4[(size_t)(p2 >> 17) * DIM4 + lane];
        float4 h3 = h4[(size_t)(p3 & 0x1FFFF) * DIM4 + lane];
        float4 r3 = emb4[(size_t)(p3 >> 17) * DIM4 + lane];
        add4(a, h0, r0);
        add4(a, h1, r1);
        add4(a, h2, r2);
        add4(a, h3, r3);
    }
    for (; e < end; ++e) {
        unsigned p0 = buckets[e];
        float4 h0 = h4[(size_t)(p0 & 0x1FFFF) * DIM4 + lane];
        float4 r0 = emb4[(size_t)(p0 >> 17) * DIM4 + lane];
        add4(a, h0, r0);
    }
    float nm = norm[n];
    a.x *= nm; a.y *= nm; a.z *= nm; a.w *= nm;
    aggn4[(size_t)n * DIM4 + lane] = a;
}

// ---------- k5: GEMM ------------------------------------------------------
// As[n][0:128] = aggn[n]; As[n][128:256] = h[n].
// out[n] = relu( As[:,0:128] @ Wn + As[:,128:256] @ (deg>0 ? Wl : We) )
__device__ inline void accum_uniform(const float4* __restrict__ W4,
                                     const float (*As)[256],
                                     int n0, int koff, int cg, float4* accv)
{
    for (int k = 0; k < DIM; k += 4) {
        float4 w0 = W4[(k + 0) * DIM4 + cg];
        float4 w1 = W4[(k + 1) * DIM4 + cg];
        float4 w2 = W4[(k + 2) * DIM4 + cg];
        float4 w3 = W4[(k + 3) * DIM4 + cg];
        #pragma unroll
        for (int i = 0; i < 8; ++i) {
            float4 a = *((const float4*)&As[n0 + i][koff + k]);
            fma4(accv[i], a.x, w0);
            fma4(accv[i], a.y, w1);
            fma4(accv[i], a.z, w2);
            fma4(accv[i], a.w, w3);
        }
    }
}

__global__ __launch_bounds__(256) void gemm_kernel(
    const float4* __restrict__ aggn4,  // [N][32]
    const float4* __restrict__ h4,     // [N][32]
    const int* __restrict__ deg,       // [N]
    const float4* __restrict__ Wn4,    // [128][32]
    const float4* __restrict__ Wl4,
    const float4* __restrict__ We4,
    float4* __restrict__ out4,         // [N][32]
    int N)
{
    __shared__ float As[64][256];      // 64 KB
    int t = threadIdx.x;
    int nbase = blockIdx.x * 64;

    // load: 4096 float4 slots, 16 per thread
    #pragma unroll
    for (int i = 0; i < 16; ++i) {
        int linear = t + i * 256;        // 0..4095
        int node = linear >> 6;          // 0..63
        int q = linear & 63;             // 0..63
        int gn = nbase + node;
        float4 v = make_float4(0.f, 0.f, 0.f, 0.f);
        if (gn < N) {
            v = (q < DIM4) ? aggn4[(size_t)gn * DIM4 + q]
                           : h4[(size_t)gn * DIM4 + (q - DIM4)];
        }
        *((float4*)&As[node][q * 4]) = v;
    }
    __syncthreads();

    int cg = t & 31;
    int ng = t >> 5;
    int n0 = ng * 8;

    float4 accv[8];
    #pragma unroll
    for (int i = 0; i < 8; ++i) accv[i] = make_float4(0.f, 0.f, 0.f, 0.f);

    accum_uniform(Wn4, As, n0, 0, cg, accv);

    bool m[8];
    bool all1 = true, all0 = true;
    #pragma unroll
    for (int i = 0; i < 8; ++i) {
        int gn = nbase + n0 + i;
        bool mi = (gn < N) ? (deg[gn] > 0) : true;
        m[i] = mi;
        all1 &= mi;
        all0 &= !mi;
    }
    if (all1) {
        accum_uniform(Wl4, As, n0, DIM, cg, accv);
    } else if (all0) {
        accum_uniform(We4, As, n0, DIM, cg, accv);
    } else {
        for (int k = 0; k < DIM; k += 4) {
            float4 l0 = Wl4[(k + 0) * DIM4 + cg];
            float4 l1 = Wl4[(k + 1) * DIM4 + cg];
            float4 l2 = Wl4[(k + 2) * DIM4 + cg];
            float4 l3 = Wl4[(k + 3) * DIM4 + cg];
            float4 e0 = We4[(k + 0) * DIM4 + cg];
            float4 e1 = We4[(k + 1) * DIM4 + cg];
            float4 e2 = We4[(k + 2) * DIM4 + cg];
            float4 e3 = We4[(k + 3) * DIM4 + cg];
            #pragma unroll
            for (int i = 0; i < 8; ++i) {
                float4 a = *((const float4*)&As[n0 + i][DIM + k]);
                float4 w0 = m[i] ? l0 : e0;
                float4 w1 = m[i] ? l1 : e1;
                float4 w2 = m[i] ? l2 : e2;
                float4 w3 = m[i] ? l3 : e3;
                fma4(accv[i], a.x, w0);
                fma4(accv[i], a.y, w1);
                fma4(accv[i], a.z, w2);
                fma4(accv[i], a.w, w3);
            }
        }
    }

    #pragma unroll
    for (int i = 0; i < 8; ++i) {
        int gn = nbase + n0 + i;
        if (gn < N) {
            float4 r = accv[i];
            r.x = fmaxf(r.x, 0.f);
            r.y = fmaxf(r.y, 0.f);
            r.z = fmaxf(r.z, 0.f);
            r.w = fmaxf(r.w, 0.f);
            out4[(size_t)gn * DIM4 + cg] = r;
        }
    }
}

extern "C" void kernel_launch(void* const* d_in, const int* in_sizes, int n_in,
                              void* d_out, int out_size, void* d_ws, size_t ws_size,
                              hipStream_t stream)
{
    const float* h    = (const float*)d_in[0];
    const float* norm = (const float*)d_in[1];
    const float* emb  = (const float*)d_in[2];
    const float* Wn   = (const float*)d_in[3];
    const float* Wl   = (const float*)d_in[4];
    const float* We   = (const float*)d_in[5];
    const int* src    = (const int*)d_in[6];
    const int* dst    = (const int*)d_in[7];
    const int* etype  = (const int*)d_in[8];

    const int N = in_sizes[1];
    const int E = in_sizes[6];

    // ws layout: deg[N] | counter[1] | cursor[N] | buckets[E] | aggn[N*128]
    int* deg        = (int*)d_ws;
    int* counter    = deg + N;
    int* cursor     = counter + 1;
    unsigned* buckets = (unsigned*)(cursor + N);
    float* aggn     = (float*)(buckets + E);

    hipMemsetAsync(d_ws, 0, (size_t)(N + 1) * sizeof(int), stream);

    deg_kernel<<<dim3((E / 4 + 255) / 256), dim3(256), 0, stream>>>(
        (const int4*)dst, deg, E / 4);

    alloc_kernel<<<dim3((N + 255) / 256), dim3(256), 0, stream>>>(
        deg, counter, cursor, N);

    fill_kernel<<<dim3((E + 255) / 256), dim3(256), 0, stream>>>(
        src, dst, etype, cursor, buckets, E);

    gather_kernel<<<dim3((N + 7) / 8), dim3(256), 0, stream>>>(
        (const float4*)h, (const float4*)emb, norm, deg, cursor, buckets,
        (float4*)aggn, N);

    gemm_kernel<<<dim3((N + 63) / 64), dim3(256), 0, stream>>>(
        (const float4*)aggn, (const float4*)h, deg,
        (const float4*)Wn, (const float4*)Wl, (const float4*)We,
        (float4*)d_out, N);
}

// Round 4
// 212.204 us; speedup vs baseline: 5.8043x; 1.4188x over previous
//
#include <hip/hip_runtime.h>
#include <hip/hip_bf16.h>

// N=50000, E=600000, D=128, R=500 — fp32 inputs, bf16-tolerant check (thr 0.535).
// out = relu( (gather_sum(h[src]+emb[etype]) * norm) @ Wn + h @ (deg>0 ? Wl : We) )
// R4: GEMM -> bf16 MFMA (B packed in regs, A streamed, no LDS); gather -> bf16
// (half the bytes); rare deg==0 nodes fixed up exactly in fp32.

#define DIM 128

typedef __attribute__((ext_vector_type(8))) short bf16x8_t;
typedef __attribute__((ext_vector_type(4))) float f32x4_t;

__device__ inline ushort f2bf(float f) {
    __hip_bfloat16 b = __float2bfloat16(f);
    return *reinterpret_cast<ushort*>(&b);
}
__device__ inline float bf2f(ushort u) {
    unsigned v = ((unsigned)u) << 16;
    return __uint_as_float(v);
}

// ---------- conv: fp32 -> bf16, 8 elems/thread ----------------------------
__global__ __launch_bounds__(256) void conv_bf16_kernel(
    const float4* __restrict__ in4, uint4* __restrict__ out8, int count8)
{
    int i = blockIdx.x * 256 + threadIdx.x;
    if (i >= count8) return;
    float4 a = in4[2 * i], b = in4[2 * i + 1];
    uint4 o;
    o.x = f2bf(a.x) | ((unsigned)f2bf(a.y) << 16);
    o.y = f2bf(a.z) | ((unsigned)f2bf(a.w) << 16);
    o.z = f2bf(b.x) | ((unsigned)f2bf(b.y) << 16);
    o.w = f2bf(b.z) | ((unsigned)f2bf(b.w) << 16);
    out8[i] = o;
}

// ---------- conv: pack stacked [Wn;Wl] into MFMA B-frag layout -------------
// Bpack[(((nt*8+ks)*64+lane)*8+j)] = W[k=ks*32+(lane>>4)*8+j][n=nt*16+(lane&15)]
__global__ __launch_bounds__(256) void pack_b_kernel(
    const float* __restrict__ Wn, const float* __restrict__ Wl,
    ushort* __restrict__ Bpack)
{
    int flat = blockIdx.x * 256 + threadIdx.x;   // 0..32767
    int j    = flat & 7;
    int lane = (flat >> 3) & 63;
    int ks   = (flat >> 9) & 7;
    int nt   = flat >> 12;
    int k = ks * 32 + (lane >> 4) * 8 + j;
    int n = nt * 16 + (lane & 15);
    float v = (k < DIM) ? Wn[k * DIM + n] : Wl[(k - DIM) * DIM + n];
    Bpack[flat] = f2bf(v);
}

// ---------- k1: in-degree histogram ---------------------------------------
__global__ __launch_bounds__(256) void deg_kernel(
    const int4* __restrict__ dst4, int* __restrict__ deg, int E4,
    const int* __restrict__ dst, int E)
{
    int i = blockIdx.x * 256 + threadIdx.x;
    if (i < E4) {
        int4 d = dst4[i];
        atomicAdd(deg + d.x, 1);
        atomicAdd(deg + d.y, 1);
        atomicAdd(deg + d.z, 1);
        atomicAdd(deg + d.w, 1);
    }
    if (i == 0)
        for (int e = E4 * 4; e < E; ++e) atomicAdd(deg + dst[e], 1);
}

// ---------- k2: offset alloc (wave scan + 1 atomic/wave) + zero-deg list --
__global__ __launch_bounds__(256) void alloc_kernel(
    const int* __restrict__ deg, int* __restrict__ counter,
    int* __restrict__ zcount, int* __restrict__ cursor,
    int* __restrict__ zlist, int N)
{
    int n = blockIdx.x * 256 + threadIdx.x;
    int lane = threadIdx.x & 63;
    int x = (n < N) ? deg[n] : 0;
    int incl = x;
    #pragma unroll
    for (int o = 1; o < 64; o <<= 1) {
        int v = __shfl_up(incl, o);
        if (lane >= o) incl += v;
    }
    int total = __shfl(incl, 63);
    int base = 0;
    if (lane == 0) base = atomicAdd(counter, total);
    base = __shfl(base, 0);
    if (n < N) {
        cursor[n] = base + incl - x;   // exclusive start
        if (x == 0) {
            int p = atomicAdd(zcount, 1);
            zlist[p] = n;
        }
    }
}

// ---------- k3: bucket fill (after: cursor[n] == end offset) ---------------
__global__ __launch_bounds__(256) void fill_kernel(
    const int4* __restrict__ src4, const int4* __restrict__ dst4,
    const int4* __restrict__ et4, int* __restrict__ cursor,
    unsigned* __restrict__ buckets, int E4,
    const int* __restrict__ src, const int* __restrict__ dst,
    const int* __restrict__ etype, int E)
{
    int i = blockIdx.x * 256 + threadIdx.x;
    if (i < E4) {
        int4 s = src4[i], d = dst4[i], t = et4[i];
        int p;
        p = atomicAdd(cursor + d.x, 1); buckets[p] = (unsigned)s.x | ((unsigned)t.x << 17);
        p = atomicAdd(cursor + d.y, 1); buckets[p] = (unsigned)s.y | ((unsigned)t.y << 17);
        p = atomicAdd(cursor + d.z, 1); buckets[p] = (unsigned)s.z | ((unsigned)t.z << 17);
        p = atomicAdd(cursor + d.w, 1); buckets[p] = (unsigned)s.w | ((unsigned)t.w << 17);
    }
    if (i == 0)
        for (int e = E4 * 4; e < E; ++e) {
            int p = atomicAdd(cursor + dst[e], 1);
            buckets[p] = (unsigned)src[e] | ((unsigned)etype[e] << 17);
        }
}

// ---------- k4: bf16 gather-reduce ----------------------------------------
// 16 lanes/node, 16B (8 bf16) per lane; 4-edge unroll = 8 gathers in flight.
__device__ inline void addbf8(float* a, uint4 hv, uint4 rv) {
    a[0] += bf2f((ushort)(hv.x & 0xFFFF)) + bf2f((ushort)(rv.x & 0xFFFF));
    a[1] += bf2f((ushort)(hv.x >> 16))    + bf2f((ushort)(rv.x >> 16));
    a[2] += bf2f((ushort)(hv.y & 0xFFFF)) + bf2f((ushort)(rv.y & 0xFFFF));
    a[3] += bf2f((ushort)(hv.y >> 16))    + bf2f((ushort)(rv.y >> 16));
    a[4] += bf2f((ushort)(hv.z & 0xFFFF)) + bf2f((ushort)(rv.z & 0xFFFF));
    a[5] += bf2f((ushort)(hv.z >> 16))    + bf2f((ushort)(rv.z >> 16));
    a[6] += bf2f((ushort)(hv.w & 0xFFFF)) + bf2f((ushort)(rv.w & 0xFFFF));
    a[7] += bf2f((ushort)(hv.w >> 16))    + bf2f((ushort)(rv.w >> 16));
}

__global__ __launch_bounds__(256) void gather_kernel(
    const uint4* __restrict__ h8,      // [N][16]
    const uint4* __restrict__ emb8,    // [R][16]
    const float* __restrict__ norm,
    const int* __restrict__ deg,
    const int* __restrict__ cursor,
    const unsigned* __restrict__ buckets,
    uint4* __restrict__ aggn8,         // [N][16] bf16
    int N)
{
    int n = blockIdx.x * 16 + (threadIdx.x >> 4);
    if (n >= N) return;
    int lane = threadIdx.x & 15;
    int end = cursor[n];
    int e   = end - deg[n];

    float a[8] = {0.f, 0.f, 0.f, 0.f, 0.f, 0.f, 0.f, 0.f};
    for (; e + 3 < end; e += 4) {
        unsigned p0 = buckets[e + 0];
        unsigned p1 = buckets[e + 1];
        unsigned p2 = buckets[e + 2];
        unsigned p3 = buckets[e + 3];
        uint4 h0 = h8[(size_t)(p0 & 0x1FFFF) * 16 + lane];
        uint4 r0 = emb8[(size_t)(p0 >> 17) * 16 + lane];
        uint4 h1 = h8[(size_t)(p1 & 0x1FFFF) * 16 + lane];
        uint4 r1 = emb8[(size_t)(p1 >> 17) * 16 + lane];
        uint4 h2 = h8[(size_t)(p2 & 0x1FFFF) * 16 + lane];
        uint4 r2 = emb8[(size_t)(p2 >> 17) * 16 + lane];
        uint4 h3 = h8[(size_t)(p3 & 0x1FFFF) * 16 + lane];
        uint4 r3 = emb8[(size_t)(p3 >> 17) * 16 + lane];
        addbf8(a, h0, r0);
        addbf8(a, h1, r1);
        addbf8(a, h2, r2);
        addbf8(a, h3, r3);
    }
    for (; e < end; ++e) {
        unsigned p0 = buckets[e];
        uint4 h0 = h8[(size_t)(p0 & 0x1FFFF) * 16 + lane];
        uint4 r0 = emb8[(size_t)(p0 >> 17) * 16 + lane];
        addbf8(a, h0, r0);
    }
    float nm = norm[n];
    uint4 o;
    o.x = f2bf(a[0] * nm) | ((unsigned)f2bf(a[1] * nm) << 16);
    o.y = f2bf(a[2] * nm) | ((unsigned)f2bf(a[3] * nm) << 16);
    o.z = f2bf(a[4] * nm) | ((unsigned)f2bf(a[5] * nm) << 16);
    o.w = f2bf(a[6] * nm) | ((unsigned)f2bf(a[7] * nm) << 16);
    aggn8[(size_t)n * 16 + lane] = o;
}

// ---------- k5: MFMA GEMM --------------------------------------------------
// A = [aggn_bf | h_bf] (N x 256 bf16), B = Bpack (256 x 128 bf16, frag layout).
// Wave: 64 cols (ch half), B in 128 VGPRs, streams 16-row tiles; 32 MFMA/tile.
// mfma_f32_16x16x32_bf16: A[m=lane&15][k=(lane>>4)*8+j]; B[k][n=lane&15];
// C/D: col=lane&15, row=(lane>>4)*4+reg.
__global__ __launch_bounds__(256) void mfma_gemm_kernel(
    const ushort* __restrict__ aggn_bf,  // [N][128]
    const ushort* __restrict__ h_bf,     // [N][128]
    const ushort* __restrict__ Bpack,    // packed
    float* __restrict__ out,             // [N][128]
    int nRowTiles, int halfWaves)
{
    int wave = threadIdx.x >> 6;
    int lane = threadIdx.x & 63;
    int wid  = blockIdx.x * 4 + wave;
    int ch   = wid & 1;                  // column half
    int w    = wid >> 1;
    int m    = lane & 15;
    int quad = lane >> 4;

    bf16x8_t b[4][8];
    #pragma unroll
    for (int nt = 0; nt < 4; ++nt)
        #pragma unroll
        for (int ks = 0; ks < 8; ++ks)
            b[nt][ks] = *(const bf16x8_t*)(Bpack +
                (((size_t)(ch * 4 + nt) * 8 + ks) * 64 + lane) * 8);

    for (int rt = w; rt < nRowTiles; rt += halfWaves) {
        size_t rowOff = (size_t)(rt * 16 + m) * DIM + quad * 8;
        bf16x8_t a[8];
        #pragma unroll
        for (int ks = 0; ks < 4; ++ks) {
            a[ks]     = *(const bf16x8_t*)(aggn_bf + rowOff + ks * 32);
            a[ks + 4] = *(const bf16x8_t*)(h_bf   + rowOff + ks * 32);
        }
        f32x4_t acc[4];
        #pragma unroll
        for (int nt = 0; nt < 4; ++nt)
            #pragma unroll
            for (int r = 0; r < 4; ++r) acc[nt][r] = 0.f;

        #pragma unroll
        for (int ks = 0; ks < 8; ++ks)
            #pragma unroll
            for (int nt = 0; nt < 4; ++nt)
                acc[nt] = __builtin_amdgcn_mfma_f32_16x16x32_bf16(
                    a[ks], b[nt][ks], acc[nt], 0, 0, 0);

        int colBase = ch * 64 + m;
        int rowBase = rt * 16 + quad * 4;
        #pragma unroll
        for (int nt = 0; nt < 4; ++nt)
            #pragma unroll
            for (int r = 0; r < 4; ++r)
                out[(size_t)(rowBase + r) * DIM + colBase + nt * 16] =
                    fmaxf(acc[nt][r], 0.f);
    }
}

// ---------- k6: exact fp32 fix-up for deg==0 nodes (expected ~0) -----------
__global__ __launch_bounds__(128) void fixup_kernel(
    const float* __restrict__ h, const float* __restrict__ We,
    const int* __restrict__ zlist, const int* __restrict__ zcount,
    float* __restrict__ out)
{
    int cnt = *zcount;
    int c = threadIdx.x;                 // column 0..127
    for (int i = blockIdx.x; i < cnt; i += gridDim.x) {
        int n = zlist[i];
        float s = 0.f;
        for (int k = 0; k < DIM; ++k)
            s = fmaf(h[(size_t)n * DIM + k], We[(size_t)k * DIM + c], s);
        out[(size_t)n * DIM + c] = fmaxf(s, 0.f);
    }
}

extern "C" void kernel_launch(void* const* d_in, const int* in_sizes, int n_in,
                              void* d_out, int out_size, void* d_ws, size_t ws_size,
                              hipStream_t stream)
{
    const float* h    = (const float*)d_in[0];
    const float* norm = (const float*)d_in[1];
    const float* emb  = (const float*)d_in[2];
    const float* Wn   = (const float*)d_in[3];
    const float* Wl   = (const float*)d_in[4];
    const float* We   = (const float*)d_in[5];
    const int* src    = (const int*)d_in[6];
    const int* dst    = (const int*)d_in[7];
    const int* etype  = (const int*)d_in[8];

    const int N = in_sizes[1];
    const int E = in_sizes[6];
    const int R = in_sizes[2] / DIM;

    // ws layout (all 16B-aligned):
    // aggn_bf[N*128]u16 | h_bf[N*128]u16 | emb_bf[R*128]u16 | Bpack[32768]u16
    // | buckets[E]u32 | deg[N] counter zcount pad pad | cursor[N] | zlist[N]
    char* p = (char*)d_ws;
    ushort* aggn_bf = (ushort*)p;             p += (size_t)N * DIM * 2;
    ushort* h_bf    = (ushort*)p;             p += (size_t)N * DIM * 2;
    ushort* emb_bf  = (ushort*)p;             p += (size_t)R * DIM * 2;
    ushort* Bpack   = (ushort*)p;             p += 2 * DIM * DIM * 2;
    unsigned* buckets = (unsigned*)p;         p += ((size_t)E * 4 + 15) & ~(size_t)15;
    int* deg     = (int*)p;                   // [N]
    int* counter = deg + N;                   // [1]
    int* zcount  = deg + N + 1;               // [1]
    int* cursor  = deg + N + 4;               // [N]
    int* zlist   = cursor + N;                // [N]

    // zero deg + counter + zcount (+pad)
    hipMemsetAsync(deg, 0, (size_t)(N + 4) * sizeof(int), stream);

    // fp32 -> bf16 conversions
    conv_bf16_kernel<<<dim3((N * DIM / 8 + 255) / 256), dim3(256), 0, stream>>>(
        (const float4*)h, (uint4*)h_bf, N * DIM / 8);
    conv_bf16_kernel<<<dim3((R * DIM / 8 + 255) / 256), dim3(256), 0, stream>>>(
        (const float4*)emb, (uint4*)emb_bf, R * DIM / 8);
    pack_b_kernel<<<dim3(2 * DIM * DIM / 256), dim3(256), 0, stream>>>(
        Wn, Wl, Bpack);

    // CSR build
    deg_kernel<<<dim3((E / 4 + 255) / 256), dim3(256), 0, stream>>>(
        (const int4*)dst, deg, E / 4, dst, E);
    alloc_kernel<<<dim3((N + 255) / 256), dim3(256), 0, stream>>>(
        deg, counter, zcount, cursor, zlist, N);
    fill_kernel<<<dim3((E / 4 + 255) / 256), dim3(256), 0, stream>>>(
        (const int4*)src, (const int4*)dst, (const int4*)etype,
        cursor, buckets, E / 4, src, dst, etype, E);

    // gather (bf16 in, fp32 accum, bf16 out)
    gather_kernel<<<dim3((N + 15) / 16), dim3(256), 0, stream>>>(
        (const uint4*)h_bf, (const uint4*)emb_bf, norm, deg, cursor, buckets,
        (uint4*)aggn_bf, N);

    // MFMA GEMM: 512 blocks * 4 waves = 2048 waves; 1024 per column half
    const int nRowTiles = N / 16;            // N=50000 -> 3125 exact
    mfma_gemm_kernel<<<dim3(512), dim3(256), 0, stream>>>(
        aggn_bf, h_bf, Bpack, (float*)d_out, nRowTiles, 1024);

    // exact fp32 fix-up for zero-in-degree nodes
    fixup_kernel<<<dim3(2), dim3(128), 0, stream>>>(
        h, We, zlist, zcount, (float*)d_out);
}

// Round 5
// 174.384 us; speedup vs baseline: 7.0632x; 1.2169x over previous
//
#include <hip/hip_runtime.h>
#include <hip/hip_bf16.h>

// N=50000, E=600000, D=128, R=500 — fp32 inputs, bf16-tolerant check (thr 0.535).
// out = relu( (gather_sum(h[src]+emb[etype]) * norm) @ Wn + h @ (deg>0 ? Wl : We) )
// R5: CSR 3-phase build (deg/scan/fill) -> one-pass linked-list bucketing
// (atomicExch head + uint2{packed,next}); 10 launches -> 5 (init/convs/pack
// fused). Gather traverses chains: one dependent 8B load per edge.

#define DIM 128

typedef __attribute__((ext_vector_type(8))) short bf16x8_t;
typedef __attribute__((ext_vector_type(4))) float f32x4_t;

__device__ inline ushort f2bf(float f) {
    __hip_bfloat16 b = __float2bfloat16(f);
    return *reinterpret_cast<ushort*>(&b);
}
__device__ inline float bf2f(ushort u) {
    unsigned v = ((unsigned)u) << 16;
    return __uint_as_float(v);
}
__device__ inline uint4 cvt8(const float4& a, const float4& b) {
    uint4 o;
    o.x = f2bf(a.x) | ((unsigned)f2bf(a.y) << 16);
    o.y = f2bf(a.z) | ((unsigned)f2bf(a.w) << 16);
    o.z = f2bf(b.x) | ((unsigned)f2bf(b.y) << 16);
    o.w = f2bf(b.z) | ((unsigned)f2bf(b.w) << 16);
    return o;
}

// ---------- k1: fused init ------------------------------------------------
// ranges: [0,nH8) h conv | [nH8,+nE8) emb conv | +32768 Bpack | +N head=-1 | +1 zcount=0
__global__ __launch_bounds__(256) void init_kernel(
    const float4* __restrict__ h4, const float4* __restrict__ emb4,
    const float* __restrict__ Wn, const float* __restrict__ Wl,
    uint4* __restrict__ h8, uint4* __restrict__ emb8,
    ushort* __restrict__ Bpack, int* __restrict__ head,
    int* __restrict__ zcount, int nH8, int nE8, int N)
{
    int i = blockIdx.x * 256 + threadIdx.x;
    if (i < nH8) {
        h8[i] = cvt8(h4[2 * i], h4[2 * i + 1]);
        return;
    }
    int j = i - nH8;
    if (j < nE8) {
        emb8[j] = cvt8(emb4[2 * j], emb4[2 * j + 1]);
        return;
    }
    j -= nE8;
    if (j < 32768) {
        // Bpack[(((nt*8+ks)*64+lane)*8+jj)] = W[ks*32+(lane>>4)*8+jj][nt*16+(lane&15)]
        int jj   = j & 7;
        int lane = (j >> 3) & 63;
        int ks   = (j >> 9) & 7;
        int nt   = j >> 12;
        int k = ks * 32 + (lane >> 4) * 8 + jj;
        int n = nt * 16 + (lane & 15);
        float v = (k < DIM) ? Wn[k * DIM + n] : Wl[(k - DIM) * DIM + n];
        Bpack[j] = f2bf(v);
        return;
    }
    j -= 32768;
    if (j < N) { head[j] = -1; return; }
    if (j == N) *zcount = 0;
}

// ---------- k2: one-pass linked-list bucketing ----------------------------
// list[e] = { src|etype<<17, prev head }; head[dst] = e.
__global__ __launch_bounds__(256) void build_kernel(
    const int4* __restrict__ src4, const int4* __restrict__ dst4,
    const int4* __restrict__ et4, int* __restrict__ head,
    uint2* __restrict__ list, int E4,
    const int* __restrict__ src, const int* __restrict__ dst,
    const int* __restrict__ etype, int E)
{
    int i = blockIdx.x * 256 + threadIdx.x;
    if (i < E4) {
        int4 s = src4[i], d = dst4[i], t = et4[i];
        int e = 4 * i;
        int old;
        old = atomicExch(head + d.x, e + 0);
        list[e + 0] = make_uint2((unsigned)s.x | ((unsigned)t.x << 17), (unsigned)old);
        old = atomicExch(head + d.y, e + 1);
        list[e + 1] = make_uint2((unsigned)s.y | ((unsigned)t.y << 17), (unsigned)old);
        old = atomicExch(head + d.z, e + 2);
        list[e + 2] = make_uint2((unsigned)s.z | ((unsigned)t.z << 17), (unsigned)old);
        old = atomicExch(head + d.w, e + 3);
        list[e + 3] = make_uint2((unsigned)s.w | ((unsigned)t.w << 17), (unsigned)old);
    }
    if (i == 0)
        for (int e = E4 * 4; e < E; ++e) {
            int old = atomicExch(head + dst[e], e);
            list[e] = make_uint2((unsigned)src[e] | ((unsigned)etype[e] << 17),
                                 (unsigned)old);
        }
}

// ---------- k3: bf16 gather over chains -----------------------------------
// 16 lanes/node, 16B/lane. Chain: one dependent 8B list load per edge;
// h/emb gathers pipeline off it. Also records zero-deg nodes.
__device__ inline void addbf8(float* a, uint4 hv, uint4 rv) {
    a[0] += bf2f((ushort)(hv.x & 0xFFFF)) + bf2f((ushort)(rv.x & 0xFFFF));
    a[1] += bf2f((ushort)(hv.x >> 16))    + bf2f((ushort)(rv.x >> 16));
    a[2] += bf2f((ushort)(hv.y & 0xFFFF)) + bf2f((ushort)(rv.y & 0xFFFF));
    a[3] += bf2f((ushort)(hv.y >> 16))    + bf2f((ushort)(rv.y >> 16));
    a[4] += bf2f((ushort)(hv.z & 0xFFFF)) + bf2f((ushort)(rv.z & 0xFFFF));
    a[5] += bf2f((ushort)(hv.z >> 16))    + bf2f((ushort)(rv.z >> 16));
    a[6] += bf2f((ushort)(hv.w & 0xFFFF)) + bf2f((ushort)(rv.w & 0xFFFF));
    a[7] += bf2f((ushort)(hv.w >> 16))    + bf2f((ushort)(rv.w >> 16));
}

__global__ __launch_bounds__(256) void gather_kernel(
    const uint4* __restrict__ h8,      // [N][16]
    const uint4* __restrict__ emb8,    // [R][16]
    const float* __restrict__ norm,
    const int* __restrict__ head,
    const uint2* __restrict__ list,
    uint4* __restrict__ aggn8,         // [N][16] bf16
    int* __restrict__ zcount, int* __restrict__ zlist,
    int N)
{
    int n = blockIdx.x * 16 + (threadIdx.x >> 4);
    if (n >= N) return;
    int lane = threadIdx.x & 15;
    int cur = head[n];

    if (cur < 0) {
        if (lane == 0) {
            int p = atomicAdd(zcount, 1);
            zlist[p] = n;
        }
        aggn8[(size_t)n * 16 + lane] = make_uint4(0, 0, 0, 0);
        return;
    }

    float a[8] = {0.f, 0.f, 0.f, 0.f, 0.f, 0.f, 0.f, 0.f};
    while (cur >= 0) {
        uint2 v = list[cur];           // {packed, next} — one 8B dependent load
        unsigned p = v.x;
        cur = (int)v.y;
        uint4 hv = h8[(size_t)(p & 0x1FFFF) * 16 + lane];
        uint4 rv = emb8[(size_t)(p >> 17) * 16 + lane];
        addbf8(a, hv, rv);
    }
    float nm = norm[n];
    uint4 o;
    o.x = f2bf(a[0] * nm) | ((unsigned)f2bf(a[1] * nm) << 16);
    o.y = f2bf(a[2] * nm) | ((unsigned)f2bf(a[3] * nm) << 16);
    o.z = f2bf(a[4] * nm) | ((unsigned)f2bf(a[5] * nm) << 16);
    o.w = f2bf(a[6] * nm) | ((unsigned)f2bf(a[7] * nm) << 16);
    aggn8[(size_t)n * 16 + lane] = o;
}

// ---------- k4: MFMA GEMM --------------------------------------------------
// A = [aggn_bf | h_bf] (N x 256 bf16), B = Bpack ([Wn;Wl], frag layout).
// Wave: 64 cols, B held in 128 VGPRs, streams 16-row A tiles, 32 MFMA/tile.
// Zero-deg rows come out as h@Wl here; fixup overwrites them exactly after.
__global__ __launch_bounds__(256) void mfma_gemm_kernel(
    const ushort* __restrict__ aggn_bf,  // [N][128]
    const ushort* __restrict__ h_bf,     // [N][128]
    const ushort* __restrict__ Bpack,
    float* __restrict__ out,             // [N][128]
    int nRowTiles, int halfWaves)
{
    int wave = threadIdx.x >> 6;
    int lane = threadIdx.x & 63;
    int wid  = blockIdx.x * 4 + wave;
    int ch   = wid & 1;                  // column half
    int w    = wid >> 1;
    int m    = lane & 15;
    int quad = lane >> 4;

    bf16x8_t b[4][8];
    #pragma unroll
    for (int nt = 0; nt < 4; ++nt)
        #pragma unroll
        for (int ks = 0; ks < 8; ++ks)
            b[nt][ks] = *(const bf16x8_t*)(Bpack +
                (((size_t)(ch * 4 + nt) * 8 + ks) * 64 + lane) * 8);

    for (int rt = w; rt < nRowTiles; rt += halfWaves) {
        size_t rowOff = (size_t)(rt * 16 + m) * DIM + quad * 8;
        bf16x8_t a[8];
        #pragma unroll
        for (int ks = 0; ks < 4; ++ks) {
            a[ks]     = *(const bf16x8_t*)(aggn_bf + rowOff + ks * 32);
            a[ks + 4] = *(const bf16x8_t*)(h_bf   + rowOff + ks * 32);
        }
        f32x4_t acc[4];
        #pragma unroll
        for (int nt = 0; nt < 4; ++nt)
            #pragma unroll
            for (int r = 0; r < 4; ++r) acc[nt][r] = 0.f;

        #pragma unroll
        for (int ks = 0; ks < 8; ++ks)
            #pragma unroll
            for (int nt = 0; nt < 4; ++nt)
                acc[nt] = __builtin_amdgcn_mfma_f32_16x16x32_bf16(
                    a[ks], b[nt][ks], acc[nt], 0, 0, 0);

        int colBase = ch * 64 + m;
        int rowBase = rt * 16 + quad * 4;
        #pragma unroll
        for (int nt = 0; nt < 4; ++nt)
            #pragma unroll
            for (int r = 0; r < 4; ++r)
                out[(size_t)(rowBase + r) * DIM + colBase + nt * 16] =
                    fmaxf(acc[nt][r], 0.f);
    }
}

// ---------- k5: exact fp32 fix-up for deg==0 nodes (expected ~0) -----------
__global__ __launch_bounds__(128) void fixup_kernel(
    const float* __restrict__ h, const float* __restrict__ We,
    const int* __restrict__ zlist, const int* __restrict__ zcount,
    float* __restrict__ out)
{
    int cnt = *zcount;
    int c = threadIdx.x;                 // column 0..127
    for (int i = blockIdx.x; i < cnt; i += gridDim.x) {
        int n = zlist[i];
        float s = 0.f;
        for (int k = 0; k < DIM; ++k)
            s = fmaf(h[(size_t)n * DIM + k], We[(size_t)k * DIM + c], s);
        out[(size_t)n * DIM + c] = fmaxf(s, 0.f);
    }
}

extern "C" void kernel_launch(void* const* d_in, const int* in_sizes, int n_in,
                              void* d_out, int out_size, void* d_ws, size_t ws_size,
                              hipStream_t stream)
{
    const float* h    = (const float*)d_in[0];
    const float* norm = (const float*)d_in[1];
    const float* emb  = (const float*)d_in[2];
    const float* Wn   = (const float*)d_in[3];
    const float* Wl   = (const float*)d_in[4];
    const float* We   = (const float*)d_in[5];
    const int* src    = (const int*)d_in[6];
    const int* dst    = (const int*)d_in[7];
    const int* etype  = (const int*)d_in[8];

    const int N = in_sizes[1];
    const int E = in_sizes[6];
    const int R = in_sizes[2] / DIM;

    // ws layout (16B-aligned pieces):
    // h_bf[N*128]u16 | emb_bf[R*128]u16 | Bpack[32768]u16 | aggn_bf[N*128]u16
    // | list[E]uint2 | head[N] | zcount[1]+pad | zlist[N]
    char* p = (char*)d_ws;
    ushort* h_bf    = (ushort*)p;  p += (size_t)N * DIM * 2;
    ushort* emb_bf  = (ushort*)p;  p += (size_t)R * DIM * 2;
    ushort* Bpack   = (ushort*)p;  p += 2 * DIM * DIM * 2;
    ushort* aggn_bf = (ushort*)p;  p += (size_t)N * DIM * 2;
    uint2*  list    = (uint2*)p;   p += (size_t)E * 8;
    int*    head    = (int*)p;     p += ((size_t)N * 4 + 15) & ~(size_t)15;
    int*    zcount  = (int*)p;     p += 16;
    int*    zlist   = (int*)p;

    const int nH8 = N * DIM / 8;
    const int nE8 = R * DIM / 8;
    const int initTotal = nH8 + nE8 + 32768 + N + 1;

    init_kernel<<<dim3((initTotal + 255) / 256), dim3(256), 0, stream>>>(
        (const float4*)h, (const float4*)emb, Wn, Wl,
        (uint4*)h_bf, (uint4*)emb_bf, Bpack, head, zcount, nH8, nE8, N);

    build_kernel<<<dim3((E / 4 + 255) / 256), dim3(256), 0, stream>>>(
        (const int4*)src, (const int4*)dst, (const int4*)etype,
        head, list, E / 4, src, dst, etype, E);

    gather_kernel<<<dim3((N + 15) / 16), dim3(256), 0, stream>>>(
        (const uint4*)h_bf, (const uint4*)emb_bf, norm, head, list,
        (uint4*)aggn_bf, zcount, zlist, N);

    const int nRowTiles = (N + 15) / 16;     // N=50000 -> 3125 exact
    mfma_gemm_kernel<<<dim3(512), dim3(256), 0, stream>>>(
        aggn_bf, h_bf, Bpack, (float*)d_out, nRowTiles, 1024);

    fixup_kernel<<<dim3(2), dim3(128), 0, stream>>>(
        h, We, zlist, zcount, (float*)d_out);
}